// Round 1
// baseline (152.069 us; speedup 1.0000x reference)
//
#include <hip/hip_runtime.h>
#include <math.h>

// NeRF two-pass renderer. One wave (64 lanes) per ray; 4 waves per block.
// B=65536 rays, KC=64 coarse, KF=64 fine, HID=32.
//
// Layer-1 factorization: (o + z*d) @ W1 + b1 = a + z*c, with a,c per-ray
// (32 floats each) in LDS. W2 (32x4) in per-lane registers.

__device__ __forceinline__ float fast_rcp(float x) { return __builtin_amdgcn_rcpf(x); }
__device__ __forceinline__ float fsigmoid(float x) { return fast_rcp(1.0f + __expf(-x)); }

__global__ __launch_bounds__(256) void nerf_render(
    const float* __restrict__ rays,      // (B,8)  o(3) d(3) near far
    const float* __restrict__ u_coarse,  // (B,64)
    const float* __restrict__ u_fine,    // (B,64)
    const float* __restrict__ u_jitter,  // (B,64)
    const float* __restrict__ W1,        // (3,32)
    const float* __restrict__ b1,        // (32,)
    const float* __restrict__ W2,        // (32,4)
    const float* __restrict__ b2,        // (4,)
    float* __restrict__ out)             // (B,8)  rgb_f, depth_f, rgb_c, depth_c
{
    __shared__ float acS[4][64];   // per wave: a[0..31], c[0..31]
    __shared__ float zS[4][128];   // per wave: merged sorted z

    const int lane = threadIdx.x & 63;
    const int wv   = threadIdx.x >> 6;
    const int ray  = (blockIdx.x << 2) + wv;

    const float* rp = rays + ray * 8;
    const float ox = rp[0], oy = rp[1], oz = rp[2];
    const float ddx = rp[3], ddy = rp[4], ddz = rp[5];
    const float nearv = rp[6], farv = rp[7];

    // W2 into registers (compile-time indexed -> VGPRs)
    float4 W2r[32];
#pragma unroll
    for (int j = 0; j < 32; ++j) W2r[j] = reinterpret_cast<const float4*>(W2)[j];
    const float4 b2v = *reinterpret_cast<const float4*>(b2);

    // cooperative a/c computation: lanes 0..31 -> a[j], lanes 32..63 -> c[j]
    {
        const int j = lane & 31;
        const float w0 = W1[j], w1 = W1[32 + j], w2 = W1[64 + j];
        const bool isA = lane < 32;
        const float px = isA ? ox : ddx;
        const float py = isA ? oy : ddy;
        const float pz = isA ? oz : ddz;
        const float bb = isA ? b1[j] : 0.0f;
        acS[wv][lane] = fmaf(px, w0, fmaf(py, w1, fmaf(pz, w2, bb)));
    }
    __syncthreads();

    const float* __restrict__ aw = &acS[wv][0];
    const float* __restrict__ cw = &acS[wv][32];

    // MLP: h = relu(a + z*c) (32); out4 = h @ W2 + b2; rgb=sigmoid, sigma raw
    auto mlp = [&](float z, float& rr, float& gg, float& bb_, float& sg) {
        float a0 = b2v.x, a1 = b2v.y, a2 = b2v.z, a3 = b2v.w;
#pragma unroll
        for (int j = 0; j < 32; j += 4) {
            const float4 av = *reinterpret_cast<const float4*>(aw + j);
            const float4 cv = *reinterpret_cast<const float4*>(cw + j);
            float h;
            h = fmaxf(fmaf(z, cv.x, av.x), 0.0f);
            a0 = fmaf(h, W2r[j+0].x, a0); a1 = fmaf(h, W2r[j+0].y, a1);
            a2 = fmaf(h, W2r[j+0].z, a2); a3 = fmaf(h, W2r[j+0].w, a3);
            h = fmaxf(fmaf(z, cv.y, av.y), 0.0f);
            a0 = fmaf(h, W2r[j+1].x, a0); a1 = fmaf(h, W2r[j+1].y, a1);
            a2 = fmaf(h, W2r[j+1].z, a2); a3 = fmaf(h, W2r[j+1].w, a3);
            h = fmaxf(fmaf(z, cv.z, av.z), 0.0f);
            a0 = fmaf(h, W2r[j+2].x, a0); a1 = fmaf(h, W2r[j+2].y, a1);
            a2 = fmaf(h, W2r[j+2].z, a2); a3 = fmaf(h, W2r[j+2].w, a3);
            h = fmaxf(fmaf(z, cv.w, av.w), 0.0f);
            a0 = fmaf(h, W2r[j+3].x, a0); a1 = fmaf(h, W2r[j+3].y, a1);
            a2 = fmaf(h, W2r[j+3].z, a2); a3 = fmaf(h, W2r[j+3].w, a3);
        }
        rr = fsigmoid(a0); gg = fsigmoid(a1); bb_ = fsigmoid(a2); sg = a3;
    };

    // ---------------- coarse pass ----------------
    const float uc = u_coarse[ray * 64 + lane];
    // bit-match reference: z_steps = k*(1/64) + u*(1/64)
    const float zsc = (float)lane * 0.015625f + uc * 0.015625f;
    const float zc = nearv * (1.0f - zsc) + farv * zsc;

    const float zcn = __shfl_down(zc, 1);
    const float deltac = (lane == 63) ? (farv - zc) : (zcn - zc);

    float cr_, cg_, cb_, csig;
    mlp(zc, cr_, cg_, cb_, csig);
    const float alphac = 1.0f - __expf(-deltac * fmaxf(csig, 0.0f));
    const float sc = 1.0f - alphac + 1e-10f;

    // exclusive prefix product of sc -> transmittance
    float p = sc;
#pragma unroll
    for (int off = 1; off < 64; off <<= 1) {
        const float t = __shfl_up(p, off);
        if (lane >= off) p *= t;
    }
    float Tc = __shfl_up(p, 1);
    if (lane == 0) Tc = 1.0f;
    const float wc = alphac * Tc;

    float rc = wc * cr_, gc = wc * cg_, bc = wc * cb_, dc = wc * zc;
#pragma unroll
    for (int off = 32; off; off >>= 1) {
        rc += __shfl_xor(rc, off);
        gc += __shfl_xor(gc, off);
        bc += __shfl_xor(bc, off);
        dc += __shfl_xor(dc, off);
    }

    // ---------------- fine sampling (inverse CDF) ----------------
    const float wp = wc + 1e-5f;
    float tot = wp;
#pragma unroll
    for (int off = 32; off; off >>= 1) tot += __shfl_xor(tot, off);
    const float pdf = wp / tot;
    float cdf = pdf;  // inclusive prefix sum
#pragma unroll
    for (int off = 1; off < 64; off <<= 1) {
        const float t = __shfl_up(cdf, off);
        if (lane >= off) cdf += t;
    }

    const float uf = u_fine[ray * 64 + lane];
    // inds = #{k in 1..64 : cdf_incl[k] <= u}  (== searchsorted_right - 1, clamped)
    int cnt = 0;
#pragma unroll
    for (int step = 64; step >= 1; step >>= 1) {
        const int idx = cnt + step - 1;
        const float v = __shfl(cdf, idx < 64 ? idx : 63);
        if (idx < 64 && v <= uf) cnt += step;
    }
    const float uj = u_jitter[ray * 64 + lane];
    const float zsf = ((float)cnt + uj) * 0.015625f;
    float zf = nearv * (1.0f - zsf) + farv * zsf;

    // ---------------- sort fine z (bitonic, 64 lanes) ----------------
#pragma unroll
    for (int k = 2; k <= 64; k <<= 1) {
#pragma unroll
        for (int j = k >> 1; j > 0; j >>= 1) {
            const float v = __shfl_xor(zf, j);
            const bool keepMin = (((lane & j) == 0) == ((lane & k) == 0));
            zf = keepMin ? fminf(zf, v) : fmaxf(zf, v);
        }
    }

    // ---------------- merge by rank into zS ----------------
    // coarse element: pos = lane + #{fine < zc}   (strict: stable-sort tie order)
    int cf = 0;
#pragma unroll
    for (int step = 64; step >= 1; step >>= 1) {
        const int idx = cf + step - 1;
        const float v = __shfl(zf, idx < 64 ? idx : 63);
        if (idx < 64 && v < zc) cf += step;
    }
    // fine element: pos = lane + #{coarse <= zf}
    int cc = 0;
#pragma unroll
    for (int step = 64; step >= 1; step >>= 1) {
        const int idx = cc + step - 1;
        const float v = __shfl(zc, idx < 64 ? idx : 63);
        if (idx < 64 && v <= zf) cc += step;
    }
    zS[wv][lane + cf] = zc;
    zS[wv][lane + cc] = zf;
    __syncthreads();

    // ---------------- fine pass (2 samples / lane) ----------------
    const float2 zz = *reinterpret_cast<const float2*>(&zS[wv][2 * lane]);
    const float z0 = zz.x, z1 = zz.y;
    const float z2n = zS[wv][(2 * lane + 2) & 127];
    const float d0 = z1 - z0;
    const float d1 = (lane == 63) ? (farv - z1) : (z2n - z1);

    float r0, g0, b0, s0, r1, g1, b1_, s1;
    mlp(z0, r0, g0, b0, s0);
    mlp(z1, r1, g1, b1_, s1);
    const float al0 = 1.0f - __expf(-d0 * fmaxf(s0, 0.0f));
    const float al1 = 1.0f - __expf(-d1 * fmaxf(s1, 0.0f));
    const float t0 = 1.0f - al0 + 1e-10f;
    const float t1 = 1.0f - al1 + 1e-10f;

    float pp = t0 * t1;  // pair product, then exclusive scan across lanes
#pragma unroll
    for (int off = 1; off < 64; off <<= 1) {
        const float t = __shfl_up(pp, off);
        if (lane >= off) pp *= t;
    }
    float Te = __shfl_up(pp, 1);
    if (lane == 0) Te = 1.0f;
    const float w0 = al0 * Te;
    const float w1 = al1 * (Te * t0);

    float fr = fmaf(w0, r0, w1 * r1);
    float fg = fmaf(w0, g0, w1 * g1);
    float fb = fmaf(w0, b0, w1 * b1_);
    float fd = fmaf(w0, z0, w1 * z1);
#pragma unroll
    for (int off = 32; off; off >>= 1) {
        fr += __shfl_xor(fr, off);
        fg += __shfl_xor(fg, off);
        fb += __shfl_xor(fb, off);
        fd += __shfl_xor(fd, off);
    }

    if (lane == 0) {
        float4* op = reinterpret_cast<float4*>(out + ray * 8);
        op[0] = make_float4(fr, fg, fb, fd);
        op[1] = make_float4(rc, gc, bc, dc);
    }
}

extern "C" void kernel_launch(void* const* d_in, const int* in_sizes, int n_in,
                              void* d_out, int out_size, void* d_ws, size_t ws_size,
                              hipStream_t stream) {
    const float* rays     = (const float*)d_in[0];
    const float* u_coarse = (const float*)d_in[1];
    const float* u_fine   = (const float*)d_in[2];
    const float* u_jitter = (const float*)d_in[3];
    const float* W1       = (const float*)d_in[4];
    const float* b1       = (const float*)d_in[5];
    const float* W2       = (const float*)d_in[6];
    const float* b2       = (const float*)d_in[7];
    float* out = (float*)d_out;

    const int B = in_sizes[0] / 8;          // 65536
    dim3 grid(B / 4), block(256);           // one wave per ray, 4 waves/block
    hipLaunchKernelGGL(nerf_render, grid, block, 0, stream,
                       rays, u_coarse, u_fine, u_jitter, W1, b1, W2, b2, out);
}